// Round 8
// baseline (195.175 us; speedup 1.0000x reference)
//
#include <hip/hip_runtime.h>
#include <hip/hip_bf16.h>
#include <stdint.h>

#define DEV __device__ __forceinline__

typedef __attribute__((ext_vector_type(8))) short bf16x8;
typedef __attribute__((ext_vector_type(4))) short bf16x4;
typedef __attribute__((ext_vector_type(4))) float f32x4;
typedef unsigned short u16;

// ---- async global->LDS, 16B per lane. lds dest must be wave-uniform base. ----
DEV void gload_lds16(const void* g, void* l) {
    typedef const __attribute__((address_space(1))) unsigned int* gp_t;
    typedef __attribute__((address_space(3))) unsigned int* lp_t;
    __builtin_amdgcn_global_load_lds((gp_t)(uintptr_t)g, (lp_t)(uint32_t)(uintptr_t)l, 16, 0, 0);
}

DEV u16 f2bf(float x) {
    union { __hip_bfloat16 h; u16 u; } c;
    c.h = __float2bfloat16(x);
    return c.u;
}
// packed f32x2 -> bf16x2 (v_cvt_pk_bf16_f32 path)
DEV unsigned pack2bf(float a, float b) {
    union { __hip_bfloat162 h2; unsigned u; } cv;
    cv.h2 = __float22bfloat162_rn(make_float2(a, b));
    return cv.u;
}
DEV float bflo(unsigned u) { union { unsigned u; float f; } c; c.u = u << 16; return c.f; }
DEV float bfhi(unsigned u) { union { unsigned u; float f; } c; c.u = u & 0xffff0000u; return c.f; }

// ============================ cast fp32 -> bf16 ============================
__global__ void cast_kernel(const float* __restrict__ src, u16* __restrict__ dst, int n8) {
    int stride = gridDim.x * blockDim.x;
    for (int i = blockIdx.x * blockDim.x + threadIdx.x; i < n8; i += stride) {
        const float4* s = (const float4*)src + (size_t)i * 2;
        float4 a = s[0], b = s[1];
        union { u16 u[8]; uint4 v; } o;
        o.u[0] = f2bf(a.x); o.u[1] = f2bf(a.y); o.u[2] = f2bf(a.z); o.u[3] = f2bf(a.w);
        o.u[4] = f2bf(b.x); o.u[5] = f2bf(b.y); o.u[6] = f2bf(b.z); o.u[7] = f2bf(b.w);
        *((uint4*)dst + i) = o.v;
    }
}

// ============================ projection GEMM ==============================
DEV void gemm_body(const u16* A, const u16* Bw, const float* bias, int bias_row,
                   u16* out, int out_pitch)
{
    __shared__ char smA[16384];
    __shared__ char smB[16384];
    const int lane = threadIdx.x & 63;
    const int w    = threadIdx.x >> 6;
    const int wr   = w >> 1, wc = w & 1;
    const int l15  = lane & 15, lg = lane >> 4;

    f32x4 acc[4][4] = {};
    const char* ag = (const char*)A;
    const char* bg = (const char*)Bw;

    for (int kt = 0; kt < 4; ++kt) {
        __syncthreads();
        #pragma unroll
        for (int c = 0; c < 8; ++c) {
            int ch    = w * 8 + c;
            int loc   = ch & 15;
            int p     = loc * 1024 + lane * 16;
            int row   = p >> 7;
            int inner = (p & 127) ^ ((row & 7) << 4);
            const char* src = (ch < 16 ? ag : bg) + row * 512 + kt * 128 + inner;
            char* dst = (ch < 16 ? smA : smB) + loc * 1024;
            gload_lds16(src, dst);
        }
        __syncthreads();
        #pragma unroll
        for (int ks = 0; ks < 2; ++ks) {
            bf16x8 af[4], bfr[4];
            #pragma unroll
            for (int mi = 0; mi < 4; ++mi) {
                int row = wr * 64 + mi * 16 + l15;
                af[mi] = *(const bf16x8*)(smA + ((row * 128 + ks * 64 + lg * 16) ^ ((row & 7) << 4)));
            }
            #pragma unroll
            for (int ni = 0; ni < 4; ++ni) {
                int row = wc * 64 + ni * 16 + l15;
                bfr[ni] = *(const bf16x8*)(smB + ((row * 128 + ks * 64 + lg * 16) ^ ((row & 7) << 4)));
            }
            #pragma unroll
            for (int mi = 0; mi < 4; ++mi)
                #pragma unroll
                for (int ni = 0; ni < 4; ++ni)
                    acc[mi][ni] = __builtin_amdgcn_mfma_f32_16x16x32_bf16(af[mi], bfr[ni], acc[mi][ni], 0, 0, 0);
        }
    }
    #pragma unroll
    for (int mi = 0; mi < 4; ++mi) {
        #pragma unroll
        for (int ni = 0; ni < 4; ++ni) {
            int n_l  = wc * 64 + ni * 16 + l15;
            float bn = bias_row ? 0.f : bias[n_l];
            #pragma unroll
            for (int r = 0; r < 4; ++r) {
                int row  = wr * 64 + mi * 16 + lg * 4 + r;
                float bb = bias_row ? bias[row] : bn;
                out[(size_t)row * out_pitch + n_l] = f2bf(acc[mi][ni][r] + bb);
            }
        }
    }
}

__global__ __launch_bounds__(256) void proj_qk_kernel(
    const u16* xb, const u16* wqb, const u16* wkb,
    const float* bq, const float* bk, u16* Q, u16* K)
{
    int n0 = blockIdx.x * 128;
    int m0 = blockIdx.y * 128;
    bool isK = n0 >= 256;
    int  nl  = n0 & 255;
    gemm_body(xb + (size_t)m0 * 256, (isK ? wkb : wqb) + (size_t)nl * 256,
              (isK ? bk : bq) + nl, 0,
              (isK ? K : Q) + (size_t)m0 * 256 + nl, 256);
}

__global__ __launch_bounds__(256) void proj_v_kernel(
    const u16* wvb, const u16* xb, const float* bv, u16* Vt)
{
    int n0 = blockIdx.x * 128;
    int m0 = blockIdx.y * 128;
    gemm_body(wvb + (size_t)m0 * 256, xb + (size_t)n0 * 256, bv + m0, 1,
              Vt + (size_t)m0 * 32768 + n0, 32768);
}

// ============================ fused attention ==============================
// KV-split x2: 1024 blocks (4 waves x 16 q-rows = 64 q; kv half = 1024).
// 4 blocks/CU, 4 waves/SIMD. KVBLK=16; K slice-major [8 ks][16 kv][64B] dbuf;
// V [256 d][32B] dbuf staged per tile-PAIR at even iters. QK = 8x mfma 16x16x32;
// PV = 2x16 mfma 16x16x16 whose B-operand == QK's C-fragment (zero shuffles).
// Partials: half0 -> out (f32 raw), half1 -> p1 (bf16); (m,l) -> ml; combined
// by combine_kernel.
__global__ __launch_bounds__(256, 4) void attn_kernel(
    const u16* __restrict__ Q, const u16* __restrict__ K,
    const u16* __restrict__ Vt, float* __restrict__ out,
    u16* __restrict__ p1, float2* __restrict__ ml)
{
    __shared__ char sm[32768];
    // kbuf0 @0, kbuf1 @8192 : [8 ks][16 kv][64B], byte-in-row ^= ((kv>>1)&3)<<4
    // vbuf0 @16384, vbuf1 @24576 : [256 d][32B],  byte-in-row ^= ((d>>2)&1)<<4

    const int lane = threadIdx.x & 63;
    const int w    = threadIdx.x >> 6;
    const int l15  = lane & 15;
    const int lg   = lane >> 4;

    // XCD batch-confinement: XCD (lin&7) serves batches 2x,2x+1 -> K/V L2-resident
    const int lin  = blockIdx.x;
    const int b    = (lin & 7) * 2 + ((lin >> 3) & 1);
    const int half = (lin >> 4) & 1;
    const int qt   = lin >> 5;                    // 0..31
    const size_t tokbase = (size_t)b * 2048;
    const int q0w  = qt * 64 + w * 16;
    const int kvh  = half * 1024;

    // Q fragments (B-operand of QK x32): lane holds Q[q0w+l15][ks*32+lg*8+j]
    bf16x8 qf[8];
    {
        const char* qrow = (const char*)(Q + (tokbase + q0w + l15) * 256);
        #pragma unroll
        for (int ks = 0; ks < 8; ++ks)
            qf[ks] = *(const bf16x8*)(qrow + ks * 64 + lg * 16);
    }

    // ---- staging precompute (per-lane 32-bit offsets; uniform base bump) ----
    // K: wave w stages slices ks = 2w, 2w+1 (1KB chunks: [16 kv][64B])
    uint32_t kgo[2];
    {
        int row = lane >> 2;
        uint32_t byte = (uint32_t)((lane & 3) * 16) ^ (((row >> 1) & 3) << 4);
        kgo[0] = (uint32_t)row * 512 + (w * 2 + 0) * 64 + byte;
        kgo[1] = (uint32_t)row * 512 + (w * 2 + 1) * 64 + byte;
    }
    const char* Kg = (const char*)K + (tokbase + kvh) * 512;
    // V: wave w stages chunks cc = 4w..4w+3 (tile = cc>>3, 32 d-rows each)
    uint32_t vgo[4];
    {
        #pragma unroll
        for (int c = 0; c < 4; ++c) {
            int cc = w * 4 + c;
            int d  = (cc & 7) * 32 + (lane >> 1);
            uint32_t byte = (uint32_t)((lane & 1) * 16) ^ (((d >> 2) & 1) << 4);
            vgo[c] = (uint32_t)d * 65536 + (cc >> 3) * 32 + byte;
        }
    }
    const char* Vg = (const char*)Vt + (tokbase + kvh) * 2;

    // LDS read bases (per-lane; all reads = base + immediate)
    const int kbase = l15 * 64 + ((lg * 16) ^ (((l15 >> 1) & 3) << 4));
    const int vbase = l15 * 32 + ((lg * 8)  ^ (((l15 >> 2) & 1) << 4));
    const char* k0p = sm + kbase;
    const char* k1p = sm + 8192 + kbase;
    const char* v0p = sm + 16384 + vbase;
    const char* v1p = sm + 24576 + vbase;

    f32x4 acc[16] = {};     // O^T partial: acc[dt][r] = O[d=dt*16+lg*4+r][q=l15]
    float m_run = -1e30f;
    float l_lane = 0.f;
    const float C = 0.09016844005556021f;   // (1/16)*log2(e)

    auto stageK = [&](int t, int sel) {
        const char* gb = Kg + (size_t)t * 8192;
        gload_lds16(gb + kgo[0], sm + sel * 8192 + (w * 2 + 0) * 1024);
        gload_lds16(gb + kgo[1], sm + sel * 8192 + (w * 2 + 1) * 1024);
    };
    auto stageV2 = [&](int t0) {        // tiles t0 -> vbuf0, t0+1 -> vbuf1
        const char* gb = Vg + (size_t)t0 * 32;
        #pragma unroll
        for (int c = 0; c < 4; ++c) {
            int cc = w * 4 + c;
            gload_lds16(gb + vgo[c], sm + 16384 + (cc >> 3) * 8192 + (cc & 7) * 1024);
        }
    };
    auto qk = [&](const char* kp) -> f32x4 {
        f32x4 sa = {}, sb = {};
        #pragma unroll
        for (int ks = 0; ks < 4; ++ks) {
            bf16x8 kf = *(const bf16x8*)(kp + ks * 1024);
            sa = __builtin_amdgcn_mfma_f32_16x16x32_bf16(kf, qf[ks], sa, 0, 0, 0);
        }
        #pragma unroll
        for (int ks = 4; ks < 8; ++ks) {
            bf16x8 kf = *(const bf16x8*)(kp + ks * 1024);
            sb = __builtin_amdgcn_mfma_f32_16x16x32_bf16(kf, qf[ks], sb, 0, 0, 0);
        }
        return sa + sb;
    };

    stageK(0, 0);
    __syncthreads();

    for (int u = 0; u < 32; ++u) {
        // ---- even tile t0 = 2u: stage K(t0+1), V pair (t0,t0+1); QK only
        stageK(2 * u + 1, 1);
        stageV2(2 * u);
        f32x4 stA = qk(k0p);
        __syncthreads();

        // ---- odd tile t1 = 2u+1: stage K(t1+1); QK; softmax pair; PV pair
        if (u < 31) stageK(2 * u + 2, 0);
        f32x4 stB = qk(k1p);

        float lmax = fmaxf(fmaxf(fmaxf(stA[0], stA[1]), fmaxf(stA[2], stA[3])),
                           fmaxf(fmaxf(stB[0], stB[1]), fmaxf(stB[2], stB[3])));
        if (__any(lmax > m_run + 16.f)) {       // rare after first pair
            float rmax = lmax;
            rmax = fmaxf(rmax, __shfl_xor(rmax, 16, 64));
            rmax = fmaxf(rmax, __shfl_xor(rmax, 32, 64));
            float m_new = fmaxf(m_run, rmax);
            float rs = exp2f((m_run - m_new) * C);
            #pragma unroll
            for (int dt = 0; dt < 16; ++dt) acc[dt] *= rs;
            l_lane *= rs;
            m_run = m_new;
        }
        const float mc = m_run * C;
        float eA0 = exp2f(stA[0] * C - mc), eA1 = exp2f(stA[1] * C - mc);
        float eA2 = exp2f(stA[2] * C - mc), eA3 = exp2f(stA[3] * C - mc);
        float eB0 = exp2f(stB[0] * C - mc), eB1 = exp2f(stB[1] * C - mc);
        float eB2 = exp2f(stB[2] * C - mc), eB3 = exp2f(stB[3] * C - mc);
        l_lane += (eA0 + eA1 + eA2 + eA3) + (eB0 + eB1 + eB2 + eB3);

        // B-operand of x16 PV == QK C-fragment layout: P^T[kv=lg*4+j][q=l15]
        union { unsigned u2[2]; bf16x4 v; } pA, pB;
        pA.u2[0] = pack2bf(eA0, eA1); pA.u2[1] = pack2bf(eA2, eA3);
        pB.u2[0] = pack2bf(eB0, eB1); pB.u2[1] = pack2bf(eB2, eB3);

        #pragma unroll
        for (int dt = 0; dt < 16; ++dt) {
            bf16x4 va = *(const bf16x4*)(v0p + dt * 512);
            bf16x4 vb = *(const bf16x4*)(v1p + dt * 512);
            asm("v_mfma_f32_16x16x16_bf16 %0, %1, %2, %0"
                : "+v"(acc[dt]) : "v"(va), "v"(pA.v));
            asm("v_mfma_f32_16x16x16_bf16 %0, %1, %2, %0"
                : "+v"(acc[dt]) : "v"(vb), "v"(pB.v));
        }
        __syncthreads();
    }

    // ---- row denominator (lanes {l15, ^16, ^32, ^48} share a q-row)
    float l_row = l_lane;
    l_row += __shfl_xor(l_row, 16, 64);
    l_row += __shfl_xor(l_row, 32, 64);
    if (lg == 0)
        ml[half * 32768 + (int)tokbase + q0w + l15] = make_float2(m_run, l_row);

    // ---- epilogue: write UNNORMALIZED partial (transpose via per-wave LDS)
    float* ow = (float*)(sm + w * 4352);   // [16 q][68 f32]
    #pragma unroll
    for (int p = 0; p < 4; ++p) {
        #pragma unroll
        for (int d2 = 0; d2 < 4; ++d2) {
            const int dt = p * 4 + d2;
            #pragma unroll
            for (int r = 0; r < 4; ++r)
                ow[l15 * 68 + d2 * 16 + lg * 4 + r] = acc[dt][r];
        }
        const int row = lane >> 2;
        const int c0  = (lane & 3) * 16;
        if (half == 0) {
            #pragma unroll
            for (int i = 0; i < 4; ++i) {
                float4 v = *(const float4*)(ow + row * 68 + c0 + i * 4);
                *(float4*)(out + (tokbase + q0w + row) * 256 + p * 64 + c0 + i * 4) = v;
            }
        } else {
            #pragma unroll
            for (int i = 0; i < 4; ++i) {
                float4 v = *(const float4*)(ow + row * 68 + c0 + i * 4);
                uint2 pk2 = make_uint2(pack2bf(v.x, v.y), pack2bf(v.z, v.w));
                *(uint2*)(p1 + (tokbase + q0w + row) * 256 + p * 64 + c0 + i * 4) = pk2;
            }
        }
    }
}

// ============================ combine partials =============================
__global__ __launch_bounds__(256) void combine_kernel(
    float* __restrict__ out, const u16* __restrict__ p1,
    const float2* __restrict__ ml)
{
    const float C = 0.09016844005556021f;
    int idx = blockIdx.x * 256 + threadIdx.x;   // 1,048,576 threads
    int q = idx >> 5;                            // 0..32767 (b*2048 + row)
    int c = idx & 31;                            // 8-float chunk of d
    float2 h0 = ml[q];
    float2 h1 = ml[32768 + q];
    float M  = fmaxf(h0.x, h1.x);
    float k0 = exp2f((h0.x - M) * C);
    float k1 = exp2f((h1.x - M) * C);
    float inv = 1.f / (h0.y * k0 + h1.y * k1);
    k0 *= inv; k1 *= inv;
    size_t off = (size_t)q * 256 + c * 8;
    float4 a0 = *(const float4*)(out + off);
    float4 a1 = *(const float4*)(out + off + 4);
    uint2 u0 = *(const uint2*)(p1 + off);
    uint2 u1 = *(const uint2*)(p1 + off + 4);
    float4 r0, r1;
    r0.x = a0.x * k0 + bflo(u0.x) * k1;
    r0.y = a0.y * k0 + bfhi(u0.x) * k1;
    r0.z = a0.z * k0 + bflo(u0.y) * k1;
    r0.w = a0.w * k0 + bfhi(u0.y) * k1;
    r1.x = a1.x * k0 + bflo(u1.x) * k1;
    r1.y = a1.y * k0 + bfhi(u1.x) * k1;
    r1.z = a1.z * k0 + bflo(u1.y) * k1;
    r1.w = a1.w * k0 + bfhi(u1.y) * k1;
    *(float4*)(out + off)     = r0;
    *(float4*)(out + off + 4) = r1;
}

// ================================ launch ===================================
extern "C" void kernel_launch(void* const* d_in, const int* in_sizes, int n_in,
                              void* d_out, int out_size, void* d_ws, size_t ws_size,
                              hipStream_t stream) {
    (void)in_sizes; (void)n_in; (void)out_size; (void)ws_size;
    const float* x  = (const float*)d_in[0];
    const float* Wq = (const float*)d_in[1];
    const float* bq = (const float*)d_in[2];
    const float* Wk = (const float*)d_in[3];
    const float* bk = (const float*)d_in[4];
    const float* Wv = (const float*)d_in[5];
    const float* bv = (const float*)d_in[6];
    float* out = (float*)d_out;

    char* ws = (char*)d_ws;
    u16* xb  = (u16*)(ws);                  // reused as p1 (bf16 partial) by attn
    u16* wqb = (u16*)(ws + 16777216);
    u16* wkb = (u16*)(ws + 16908288);
    u16* wvb = (u16*)(ws + 17039360);
    u16* Qb  = (u16*)(ws + 17170432);
    u16* Kb  = (u16*)(ws + 33947648);
    u16* Vtb = (u16*)(ws + 50724864);
    float2* ml = (float2*)(ws + 67502080);  // [2 halves][32768 rows] float2

    cast_kernel<<<2048, 256, 0, stream>>>(x,  xb,  1048576);
    cast_kernel<<<64,   256, 0, stream>>>(Wq, wqb, 8192);
    cast_kernel<<<64,   256, 0, stream>>>(Wk, wkb, 8192);
    cast_kernel<<<64,   256, 0, stream>>>(Wv, wvb, 8192);

    proj_qk_kernel<<<dim3(4, 256), 256, 0, stream>>>(xb, wqb, wkb, bq, bk, Qb, Kb);
    proj_v_kernel<<<dim3(256, 2), 256, 0, stream>>>(wvb, xb, bv, Vtb);

    attn_kernel<<<1024, 256, 0, stream>>>(Qb, Kb, Vtb, out, xb, ml);
    combine_kernel<<<4096, 256, 0, stream>>>(out, xb, ml);
}